// Round 1
// baseline (49.784 us; speedup 1.0000x reference)
//
#include <hip/hip_runtime.h>
#include <math.h>

#define CC 512
#define HH 256
#define WW 256
#define RB 64    // rows per LDS tile
#define NT 256   // threads per block

__global__ __launch_bounds__(NT) void corner_pool_kernel(const float* __restrict__ x,
                                                         float* __restrict__ out) {
    __shared__ float tile[RB][WW];   // 64 KiB
    const int c    = blockIdx.x;
    const int t    = threadIdx.x;
    const int lane = t & 63;
    const int wave = t >> 6;

    const float* xc = x   + (size_t)c * HH * WW;
    float*       oc = out + (size_t)c * HH * WW;

    float cm = -INFINITY;  // running column max for column t (carried across tiles)

    for (int rb = 0; rb < HH / RB; ++rb) {
        // ---- stage 64 rows into LDS, float4 coalesced (16 B/lane) ----
        const float* src = xc + rb * RB * WW;
        #pragma unroll
        for (int i = 0; i < (RB * WW) / (NT * 4); ++i) {   // 16 iters
            int j   = i * NT + t;      // float4 index within tile
            int row = j >> 6;          // WW/4 = 64 float4 per row
            int c4  = j & 63;
            float4 v = *(const float4*)(src + row * WW + c4 * 4);
            *(float4*)&tile[row][c4 * 4] = v;
        }
        __syncthreads();

        // ---- column cummax: thread t owns column t ----
        // (2 lanes/bank LDS aliasing = conflict-free per m136)
        #pragma unroll 8
        for (int r = 0; r < RB; ++r) {
            float v = tile[r][t];
            cm = fmaxf(cm, v);
            tile[r][t] = cm;
        }
        __syncthreads();

        // ---- row prefix-max scans: wave k handles rows 16k..16k+15 ----
        #pragma unroll 4
        for (int rr = 0; rr < RB / 4; ++rr) {
            int r = wave * (RB / 4) + rr;
            float4 v = *(const float4*)&tile[r][lane * 4];
            float p0 = v.x;
            float p1 = fmaxf(p0, v.y);
            float p2 = fmaxf(p1, v.z);
            float p3 = fmaxf(p2, v.w);
            float s = p3;
            // 64-lane inclusive max-scan of per-thread totals
            #pragma unroll
            for (int d = 1; d < 64; d <<= 1) {
                float u = __shfl_up(s, d);
                if (lane >= d) s = fmaxf(s, u);
            }
            float e = __shfl_up(s, 1);           // exclusive prefix
            if (lane == 0) e = -INFINITY;
            float4 o;
            o.x = 2.0f * fmaxf(e, p0);
            o.y = 2.0f * fmaxf(e, p1);
            o.z = 2.0f * fmaxf(e, p2);
            o.w = 2.0f * fmaxf(e, p3);
            *(float4*)(oc + (size_t)(rb * RB + r) * WW + lane * 4) = o;
        }
        __syncthreads();
    }
}

extern "C" void kernel_launch(void* const* d_in, const int* in_sizes, int n_in,
                              void* d_out, int out_size, void* d_ws, size_t ws_size,
                              hipStream_t stream) {
    const float* x = (const float*)d_in[0];
    float* out = (float*)d_out;
    corner_pool_kernel<<<dim3(CC), dim3(NT), 0, stream>>>(x, out);
}

// Round 3
// 46.939 us; speedup vs baseline: 1.0606x; 1.0606x over previous
//
#include <hip/hip_runtime.h>
#include <math.h>

#define CC 512
#define HH 256
#define WW 256
#define RB 32                 // rows per tile
#define NTILES (HH / RB)      // 8
#define NT 256                // threads per block
#define RPW (RB / 4)          // rows per wave per tile = 8

typedef float f32x4 __attribute__((ext_vector_type(4)));

#define BAR()    asm volatile("s_barrier" ::: "memory")
#define WAITV(N) asm volatile("s_waitcnt vmcnt(" #N ")" ::: "memory")
#define WAITL()  asm volatile("s_waitcnt lgkmcnt(0)" ::: "memory")

// DPP move with -inf fill for invalid/masked lanes (old = -inf, bound_ctrl = false)
template<int CTRL, int ROW_MASK>
__device__ __forceinline__ float dpp_ninf(float v) {
    union { float f; int i; } o, s, r;
    o.f = -INFINITY;
    s.f = v;
    r.i = __builtin_amdgcn_update_dpp(o.i, s.i, CTRL, ROW_MASK, 0xF, false);
    return r.f;
}

// 64-lane inclusive max-scan, pure DPP/VALU (no LDS traffic)
__device__ __forceinline__ float wave_incl_max(float v) {
    v = fmaxf(v, dpp_ninf<0x111, 0xF>(v));  // row_shr:1
    v = fmaxf(v, dpp_ninf<0x112, 0xF>(v));  // row_shr:2
    v = fmaxf(v, dpp_ninf<0x114, 0xF>(v));  // row_shr:4
    v = fmaxf(v, dpp_ninf<0x118, 0xF>(v));  // row_shr:8
    v = fmaxf(v, dpp_ninf<0x142, 0xA>(v));  // row_bcast15 -> rows 1,3
    v = fmaxf(v, dpp_ninf<0x143, 0xC>(v));  // row_bcast31 -> rows 2,3
    return v;
}

__device__ __forceinline__ void stage_rows(const float* src, float* lds_row_base,
                                           int wave, int lane) {
    // one global_load_lds per row: wave-uniform LDS base + lane*16B (linear row)
    #pragma unroll
    for (int i = 0; i < RPW; ++i) {
        int r = wave * RPW + i;
        const float* g = src + r * WW + lane * 4;
        __builtin_amdgcn_global_load_lds(
            (const __attribute__((address_space(1))) void*)g,
            (__attribute__((address_space(3))) void*)(lds_row_base + r * WW),
            16, 0, 0);
    }
}

__global__ __launch_bounds__(NT) void corner_pool_kernel(const float* __restrict__ x,
                                                         float* __restrict__ out) {
    __shared__ float tile[2][RB][WW];   // 2 x 32 KiB
    const int t    = threadIdx.x;
    const int lane = t & 63;
    const int wave = t >> 6;
    const int c    = blockIdx.x;

    const float* xc = x   + (size_t)c * HH * WW;
    float*       oc = out + (size_t)c * HH * WW;

    float cm = -INFINITY;   // running column max for column t

    // prologue: stage tile 0 into buf 0
    stage_rows(xc, &tile[0][0][0], wave, lane);

    #pragma unroll
    for (int ti = 0; ti < NTILES; ++ti) {
        const int cb = ti & 1;

        // prefetch next tile into the other buffer (its readers finished at
        // the end-of-iter barrier of ti-1), keep its 8 loads in flight
        if (ti + 1 < NTILES) {
            stage_rows(xc + (size_t)(ti + 1) * RB * WW, &tile[cb ^ 1][0][0], wave, lane);
            WAITV(8);       // wait only for CUR tile's loads; 8 prefetches stay in flight
        } else {
            WAITV(0);
        }
        BAR();              // all waves' cur-tile loads landed

        // ---- column cummax: thread t owns column t ----
        #pragma unroll
        for (int r = 0; r < RB; ++r) {
            cm = fmaxf(cm, tile[cb][r][t]);
            tile[cb][r][t] = cm;
        }
        WAITL();
        BAR();              // cm writes visible to row-phase readers

        // ---- row prefix-max scans (DPP), NT store of 2*y ----
        #pragma unroll
        for (int i = 0; i < RPW; ++i) {
            int r = wave * RPW + i;
            f32x4 v = *(const f32x4*)&tile[cb][r][lane * 4];
            float p0 = v.x;
            float p1 = fmaxf(p0, v.y);
            float p2 = fmaxf(p1, v.z);
            float p3 = fmaxf(p2, v.w);
            float s  = wave_incl_max(p3);
            float e  = dpp_ninf<0x138, 0xF>(s);   // wave_shr:1 -> exclusive prefix
            f32x4 o;
            o.x = 2.0f * fmaxf(e, p0);
            o.y = 2.0f * fmaxf(e, p1);
            o.z = 2.0f * fmaxf(e, p2);
            o.w = 2.0f * fmaxf(e, p3);
            __builtin_nontemporal_store(o, (f32x4*)(oc + (size_t)(ti * RB + r) * WW + lane * 4));
        }
        BAR();              // row reads done before next iter's DMA overwrites cur
    }
}

extern "C" void kernel_launch(void* const* d_in, const int* in_sizes, int n_in,
                              void* d_out, int out_size, void* d_ws, size_t ws_size,
                              hipStream_t stream) {
    const float* x = (const float*)d_in[0];
    float* out = (float*)d_out;
    corner_pool_kernel<<<dim3(CC), dim3(NT), 0, stream>>>(x, out);
}